// Round 8
// baseline (826.838 us; speedup 1.0000x reference)
//
#include <hip/hip_runtime.h>
#include <hip/hip_bf16.h>
#include <cmath>

// CapsNet forward. conv2 = split-bf16 MFMA (3-product), conv1 fused on VALU,
// weights STAGED PER-TAP into double-buffered LDS via global_load_lds:
//   tap T: stage(T+1) -> wbuf[(T+1)&1] (async, 4x16B calls/wave),
//          ds_read A-frags (c1, stride-40) + B-frags (wbuf[T&1], kg-major),
//          18 MFMA, one barrier (vmcnt drain == stage(T+1) landed).
// wstg global layout = exact staging order: record16B[(chunk*81+tap)][s],
//   s<1024: hi (kg=s>>8, co=s&255), s>=1024: lo. LDS slot kg*256+co ->
//   8-lane read groups hit 8 contiguous 16B slots = conflict-free.
// ws (bytes): wstg 21,233,664 | xcaps 9,437,184 = 30.7 MB

typedef float f32x4 __attribute__((ext_vector_type(4)));
typedef short s16x8 __attribute__((ext_vector_type(8)));
typedef unsigned int u32;

static __device__ __forceinline__ short f2bf(float x) {
  __hip_bfloat16 h = __float2bfloat16(x);
  return *reinterpret_cast<short*>(&h);
}
static __device__ __forceinline__ float bf2f(short s) {
  __hip_bfloat16 h;
  *reinterpret_cast<short*>(&h) = s;
  return __bfloat162float(h);
}
static __device__ __forceinline__ void stage16(const short* g, short* l) {
  __builtin_amdgcn_global_load_lds(
      (const __attribute__((address_space(1))) u32*)(const void*)g,
      (__attribute__((address_space(3))) u32*)(void*)l, 16, 0, 0);
}

// ---------------- prep: w2 -> staging-order bf16 hi/lo records ----------------
__global__ __launch_bounds__(256) void prep_w2(const float* __restrict__ w2,
                                               s16x8* __restrict__ wstg) {
  const int gid = blockIdx.x * 256 + threadIdx.x;  // 663,552 = 648*1024
  const int T = gid >> 10;
  const int s = gid & 1023;
  const int kg = s >> 8, co = s & 255;
  const int chunk = T / 81, tap = T - chunk * 81;
  const float* src = w2 + ((size_t)co * 256 + chunk * 32 + kg * 8) * 81 + tap;
  s16x8 hi, lo;
#pragma unroll
  for (int i = 0; i < 8; ++i) {
    const float x = src[i * 81];
    const short h = f2bf(x);
    hi[i] = h;
    lo[i] = f2bf(x - bf2f(h));
  }
  wstg[(size_t)T * 2048 + s] = hi;
  wstg[(size_t)T * 2048 + 1024 + s] = lo;
}

// one ky-slice of a conv1 output row
static __device__ __forceinline__ void c1_slice(const float* __restrict__ simg,
                                                const float* __restrict__ w1g,
                                                int ch, int y, int ky,
                                                float* __restrict__ acc) {
  float rr[28];
#pragma unroll
  for (int q = 0; q < 7; ++q)
    *(float4*)&rr[q * 4] = *(const float4*)&simg[(y + ky) * 36 + q * 4];
  const float* wr = w1g + ch * 81 + ky * 9;
#pragma unroll
  for (int kx = 0; kx < 9; ++kx) {
    const float w = wr[kx];
#pragma unroll
    for (int x = 0; x < 20; ++x) acc[x] = fmaf(w, rr[x + kx], acc[x]);
  }
}
static __device__ __forceinline__ void store_c1(short* __restrict__ c1hi,
                                                short* __restrict__ c1lo,
                                                int ci, int y,
                                                const float* __restrict__ acc) {
  short* hp = &c1hi[(y * 20) * 40 + ci];
  short* lp = &c1lo[(y * 20) * 40 + ci];
#pragma unroll
  for (int x = 0; x < 20; ++x) {
    const float v = fmaxf(acc[x], 0.f);
    const short hi = f2bf(v);
    hp[x * 40] = hi;
    lp[x * 40] = f2bf(v - bf2f(hi));
  }
}

// ---------------- conv1 + conv2, tap-staged pipeline ----------------
__global__ __launch_bounds__(512) void conv2_mfma(
    const float* __restrict__ data, const float* __restrict__ w1,
    const float* __restrict__ b1, const short* __restrict__ wstg,
    const float* __restrict__ b2, float* __restrict__ xcaps) {
  const int t = threadIdx.x;
  const int b = blockIdx.x;
  const int lane = t & 63;
  const int wv = t >> 6;  // wave 0..7

  __shared__ float simg[28 * 36];     //  4,032 B
  __shared__ short c1hi[400 * 40];    // 32,000 B
  __shared__ short c1lo[400 * 40];    // 32,000 B
  __shared__ short wbuf[2][16384];    // 2 x 32,768 B (2048 slots x 16B)

  for (int i = t; i < 784; i += 512)
    simg[(i / 28) * 36 + (i % 28)] = data[b * 784 + i];

  const int r16 = lane & 15;
  const int kg = lane >> 4;

  int base0[3];
#pragma unroll
  for (int m = 0; m < 3; ++m) {
    int pos = m * 16 + r16;
    if (pos > 35) pos = 35;  // clamped pads: same-addr broadcast, discarded
    const int oy = pos / 6, ox = pos % 6;
    base0[m] = (oy * 40 + ox * 2) * 40 + kg * 8;
  }
  int bhOff[2], con[2];
  float bias[2];
#pragma unroll
  for (int j = 0; j < 2; ++j) {
    const int co = wv * 32 + j * 16 + r16;
    con[j] = co;
    bhOff[j] = (kg * 256 + co) * 8;  // shorts; lo at +8192
    bias[j] = b2[co];
  }

  const int ci0 = t & 31;
  const int y0 = t >> 5;  // 0..15
  const bool has1 = (t < 128);

  const f32x4 vzero = {0.f, 0.f, 0.f, 0.f};
  f32x4 acc[3][2];
#pragma unroll
  for (int m = 0; m < 3; ++m)
#pragma unroll
    for (int j = 0; j < 2; ++j) acc[m][j] = vzero;

  float accA0[20], accA1[20];

  // ---- stage T=0 (async), then conv1 chunk 0 covers its latency ----
  {
#pragma unroll
    for (int c = 0; c < 4; ++c) {
      short* dst = &wbuf[0][(wv * 256 + c * 64) * 8];
      const short* src = &wstg[((size_t)(wv * 256 + c * 64 + lane)) * 8];
      stage16(src, dst);
    }
  }
  __syncthreads();  // simg ready (stage still in flight; drained below too)
  {
    const float bz = b1[ci0];
#pragma unroll
    for (int x = 0; x < 20; ++x) accA0[x] = bz;
    for (int ky = 0; ky < 9; ++ky) c1_slice(simg, w1, ci0, y0, ky, accA0);
    store_c1(c1hi, c1lo, ci0, y0, accA0);
    if (has1) {
#pragma unroll
      for (int x = 0; x < 20; ++x) accA1[x] = bz;
      for (int ky = 0; ky < 9; ++ky) c1_slice(simg, w1, ci0, y0 + 16, ky, accA1);
      store_c1(c1hi, c1lo, ci0, y0 + 16, accA1);
    }
  }
  __syncthreads();  // c1 chunk0 visible; vmcnt(0) drain -> wbuf[0] ready

  int kx = 0, ky = 0, chunk = 0;
  for (int T = 0; T < 648; ++T) {
    // ---- stage T+1 into wbuf[(T+1)&1] (read last at T-1; barrier passed) ----
    if (T + 1 < 648) {
      const size_t tb = (size_t)(T + 1) * 2048;
#pragma unroll
      for (int c = 0; c < 4; ++c) {
        short* dst = &wbuf[(T + 1) & 1][(wv * 256 + c * 64) * 8];
        const short* src = &wstg[(tb + wv * 256 + c * 64 + lane) * 8];
        stage16(src, dst);
      }
    }
    // ---- interleaved conv1 slice for chunk+1 (registers only) ----
    if (kx == 0 && chunk < 7) {
      const int chA = (chunk + 1) * 32 + ci0;
      if (ky == 0) {
        const float bz = b1[chA];
#pragma unroll
        for (int x = 0; x < 20; ++x) { accA0[x] = bz; accA1[x] = bz; }
      }
      c1_slice(simg, w1, chA, y0, ky, accA0);
      if (has1) c1_slice(simg, w1, chA, y0 + 16, ky, accA1);
    }
    // ---- tap T: A-frags from c1, B-frags from wbuf[T&1], 18 MFMA ----
    {
      const int rowoff = (ky * 20 + kx) * 40;
      const short* wb = wbuf[T & 1];
      s16x8 AH[3], AL[3], BH[2], BL[2];
#pragma unroll
      for (int m = 0; m < 3; ++m) {
        AH[m] = *(const s16x8*)&c1hi[base0[m] + rowoff];
        AL[m] = *(const s16x8*)&c1lo[base0[m] + rowoff];
      }
#pragma unroll
      for (int j = 0; j < 2; ++j) {
        BH[j] = *(const s16x8*)&wb[bhOff[j]];
        BL[j] = *(const s16x8*)&wb[bhOff[j] + 8192];
      }
#pragma unroll
      for (int m = 0; m < 3; ++m)
#pragma unroll
        for (int j = 0; j < 2; ++j)
          acc[m][j] = __builtin_amdgcn_mfma_f32_16x16x32_bf16(AH[m], BH[j], acc[m][j], 0, 0, 0);
#pragma unroll
      for (int m = 0; m < 3; ++m)
#pragma unroll
        for (int j = 0; j < 2; ++j)
          acc[m][j] = __builtin_amdgcn_mfma_f32_16x16x32_bf16(AL[m], BH[j], acc[m][j], 0, 0, 0);
#pragma unroll
      for (int m = 0; m < 3; ++m)
#pragma unroll
        for (int j = 0; j < 2; ++j)
          acc[m][j] = __builtin_amdgcn_mfma_f32_16x16x32_bf16(AH[m], BL[j], acc[m][j], 0, 0, 0);
    }
    __syncthreads();  // drains stage(T+1); all waves done with wbuf[T&1], c1(chunk)
    // ---- advance tap / chunk counters ----
    ++kx;
    if (kx == 9) {
      kx = 0;
      ++ky;
      if (ky == 9) {
        ky = 0;
        if (chunk < 7) {
          store_c1(c1hi, c1lo, ci0, y0, accA0);
          if (has1) store_c1(c1hi, c1lo, ci0, y0 + 16, accA1);
          __syncthreads();
        }
        ++chunk;
      }
    }
  }

  // ---- store: D col=lane&15, row=(lane>>4)*4+reg; xcaps[b][n][d] ----
#pragma unroll
  for (int m = 0; m < 3; ++m) {
#pragma unroll
    for (int jj = 0; jj < 4; ++jj) {
      const int pos = m * 16 + kg * 4 + jj;
      if (pos < 36) {
#pragma unroll
        for (int j = 0; j < 2; ++j) {
          const int co = con[j];
          const int n = (co & 31) * 36 + pos;
          xcaps[((size_t)b * 1152 + n) * 8 + (co >> 5)] = acc[m][j][jj] + bias[j];
        }
      }
    }
  }
}

// ---------------- fused u_hat + routing: block per (o,b) ----------------
__global__ __launch_bounds__(256) void routing_fused(const float* __restrict__ xcaps,
                                                     const float* __restrict__ W,
                                                     float* __restrict__ out) {
  const int o = blockIdx.x >> 8;
  const int b = blockIdx.x & 255;
  const int t = threadIdx.x;
  const int k = t & 15, ng = t >> 4;
  __shared__ float xs[1152 * 9];
  __shared__ double redA[256];
  __shared__ double redB[256];
  __shared__ float s_s[16];
  __shared__ float s_sv;
  __shared__ double s_f;

  {
    const float4* src = (const float4*)(xcaps + (size_t)b * 9216);
    for (int idx = t; idx < 2304; idx += 256) {
      float4 v = src[idx];
      const int n = idx >> 1, h = idx & 1;
      float* dst = &xs[n * 9 + h * 4];
      dst[0] = v.x; dst[1] = v.y; dst[2] = v.z; dst[3] = v.w;
    }
  }
  __syncthreads();

  const int n0 = ng * 72;
  float u[72];
  const float* wp = W + ((size_t)(n0 * 10 + o) * 16 + k) * 8;
#pragma unroll
  for (int i = 0; i < 72; ++i) {
    const float* wq = wp + (size_t)i * 1280;
    const float4 wa = *(const float4*)wq;
    const float4 wb = *(const float4*)(wq + 4);
    const float* xp = &xs[(n0 + i) * 9];
    float s = fmaf(wa.x, xp[0], 0.f);
    s = fmaf(wa.y, xp[1], s);
    s = fmaf(wa.z, xp[2], s);
    s = fmaf(wa.w, xp[3], s);
    s = fmaf(wb.x, xp[4], s);
    s = fmaf(wb.y, xp[5], s);
    s = fmaf(wb.z, xp[6], s);
    s = fmaf(wb.w, xp[7], s);
    u[i] = s;
  }

  // ---- pass 1: uniform c = 1/1152 ----
  double S = 0.0;
#pragma unroll
  for (int i = 0; i < 72; ++i) S += (double)u[i];
  redA[t] = S;
  __syncthreads();
  if (t < 16) {
    double tt = 0.0;
#pragma unroll
    for (int g = 0; g < 16; ++g) tt += redA[g * 16 + t];
    s_s[t] = (float)(tt * (double)(1.0f / 1152.0f));
  }
  __syncthreads();
  if (t == 0) {
    double sn = 0.0;
#pragma unroll
    for (int kk = 0; kk < 16; ++kk) sn += (double)s_s[kk] * (double)s_s[kk];
    const double f = sn / ((1.0 + sn) * sqrt(sn));
    double sv = 0.0;
#pragma unroll
    for (int kk = 0; kk < 16; ++kk) sv += (double)s_s[kk] * f;
    s_sv = (float)sv;
  }
  __syncthreads();
  const float sv1 = s_sv;

  // ---- pass 2 ----
  double E = 0.0, EU = 0.0;
#pragma unroll
  for (int i = 0; i < 72; ++i) {
    const float e = expf(u[i] * sv1);
    E += (double)e;
    EU += (double)e * (double)u[i];
  }
  redA[t] = E; redB[t] = EU;
  __syncthreads();
  if (t < 16) {
    double te = 0.0, tu = 0.0;
#pragma unroll
    for (int g = 0; g < 16; ++g) { te += redA[g * 16 + t]; tu += redB[g * 16 + t]; }
    s_s[t] = (float)(tu / te);
  }
  __syncthreads();
  if (t == 0) {
    double sn = 0.0;
#pragma unroll
    for (int kk = 0; kk < 16; ++kk) sn += (double)s_s[kk] * (double)s_s[kk];
    const double f = sn / ((1.0 + sn) * sqrt(sn));
    double sv = 0.0;
#pragma unroll
    for (int kk = 0; kk < 16; ++kk) sv += (double)s_s[kk] * f;
    s_sv = sv1 + (float)sv;
  }
  __syncthreads();
  const float sv12 = s_sv;

  // ---- pass 3 -> output ----
  E = 0.0; EU = 0.0;
#pragma unroll
  for (int i = 0; i < 72; ++i) {
    const float e = expf(u[i] * sv12);
    E += (double)e;
    EU += (double)e * (double)u[i];
  }
  redA[t] = E; redB[t] = EU;
  __syncthreads();
  if (t < 16) {
    double te = 0.0, tu = 0.0;
#pragma unroll
    for (int g = 0; g < 16; ++g) { te += redA[g * 16 + t]; tu += redB[g * 16 + t]; }
    s_s[t] = (float)(tu / te);
  }
  __syncthreads();
  if (t == 0) {
    double sn = 0.0;
#pragma unroll
    for (int kk = 0; kk < 16; ++kk) sn += (double)s_s[kk] * (double)s_s[kk];
    s_f = sn / ((1.0 + sn) * sqrt(sn));
  }
  __syncthreads();
  if (t < 16) out[b * 160 + o * 16 + t] = (float)((double)s_s[t] * s_f);
}

extern "C" void kernel_launch(void* const* d_in, const int* in_sizes, int n_in,
                              void* d_out, int out_size, void* d_ws, size_t ws_size,
                              hipStream_t stream) {
  const float* data = (const float*)d_in[0];
  const float* w1   = (const float*)d_in[1];
  const float* b1   = (const float*)d_in[2];
  const float* w2   = (const float*)d_in[3];
  const float* b2   = (const float*)d_in[4];
  const float* W    = (const float*)d_in[5];
  float* out = (float*)d_out;

  short* wstg  = (short*)d_ws;             // 648*2048*8 = 10,616,832 s16x8 slots
  float* xcaps = (float*)(wstg + 10616832);// 2,359,296 floats

  prep_w2<<<2592, 256, 0, stream>>>(w2, (s16x8*)wstg);
  conv2_mfma<<<256, 512, 0, stream>>>(data, w1, b1, wstg, b2, xcaps);
  routing_fused<<<2560, 256, 0, stream>>>(xcaps, W, out);
}

// Round 9
// 640.000 us; speedup vs baseline: 1.2919x; 1.2919x over previous
//
#include <hip/hip_runtime.h>
#include <hip/hip_bf16.h>
#include <cmath>

// CapsNet forward. conv2 = split-bf16 MFMA (3-product), restructured for TLP:
//  conv1_c1g : standalone conv1 -> global bf16 hi/lo, PRE-SWIZZLED slot order
//              c1g[img][chunk][row(400)][slot(8)][il(8)]; slot=(P*4+kg+kap)&7,
//              kap(row)=((rx>>1)+6*(ry>>1))&7  -> conflict-free b128 reads.
//  conv2_mfma: grid 1024 = coh(4 co-slices, major) x img(256); 256 thr/4 waves;
//              LDS = one 50 KB c1 chunk (staged via global_load_lds, 2 barriers
//              per chunk, 16 total); B-weights depth-1 register prefetch from
//              L2-resident 5.3 MB slice; 9 MFMA/tap/wave; 3 blocks/CU.
//  routing_fused: unchanged.
// ws: wstg 21.2 MB | c1g 104.9 MB | xcaps 9.4 MB = 135.5 MB

typedef float f32x4 __attribute__((ext_vector_type(4)));
typedef short s16x8 __attribute__((ext_vector_type(8)));
typedef unsigned int u32;

static __device__ __forceinline__ short f2bf(float x) {
  __hip_bfloat16 h = __float2bfloat16(x);
  return *reinterpret_cast<short*>(&h);
}
static __device__ __forceinline__ float bf2f(short s) {
  __hip_bfloat16 h;
  *reinterpret_cast<short*>(&h) = s;
  return __bfloat162float(h);
}
static __device__ __forceinline__ void stage16(const short* g, short* l) {
  __builtin_amdgcn_global_load_lds(
      (const __attribute__((address_space(1))) u32*)(const void*)g,
      (__attribute__((address_space(3))) u32*)(void*)l, 16, 0, 0);
}

// ---------------- prep: w2 -> wstg records (as R8; proven) ----------------
// slot_idx(hi) = T*2048 + kg*256 + co ; lo at +1024. T = chunk*81 + ky*9 + kx.
__global__ __launch_bounds__(256) void prep_w2(const float* __restrict__ w2,
                                               s16x8* __restrict__ wstg) {
  const int gid = blockIdx.x * 256 + threadIdx.x;  // 663,552 = 648*1024
  const int T = gid >> 10;
  const int s = gid & 1023;
  const int kg = s >> 8, co = s & 255;
  const int chunk = T / 81, tap = T - chunk * 81;
  const float* src = w2 + ((size_t)co * 256 + chunk * 32 + kg * 8) * 81 + tap;
  s16x8 hi, lo;
#pragma unroll
  for (int i = 0; i < 8; ++i) {
    const float x = src[i * 81];
    const short h = f2bf(x);
    hi[i] = h;
    lo[i] = f2bf(x - bf2f(h));
  }
  wstg[(size_t)T * 2048 + s] = hi;
  wstg[(size_t)T * 2048 + 1024 + s] = lo;
}

// ---------------- conv1 -> c1g (pre-split, pre-swizzled) ----------------
// grid 512 = img*2 + yh; 256 thr; tasks = 256 ci x 10 y-rows.
__global__ __launch_bounds__(256) void conv1_c1g(
    const float* __restrict__ data, const float* __restrict__ w1,
    const float* __restrict__ b1, short* __restrict__ c1g) {
  const int img = blockIdx.x >> 1;
  const int yh = blockIdx.x & 1;
  const int t = threadIdx.x;
  __shared__ float simg[19 * 36];
  for (int i = t; i < 19 * 28; i += 256) {
    const int r = i / 28, c = i % 28;
    if (yh * 10 + r < 28) simg[r * 36 + c] = data[img * 784 + (yh * 10 + r) * 28 + c];
  }
  __syncthreads();
  for (int task = t; task < 2560; task += 256) {
    const int ci = task & 255;
    const int yl = task >> 8;       // 0..9
    const int y = yh * 10 + yl;
    const float* wr = w1 + ci * 81;
    float acc[20];
    const float bz = b1[ci];
#pragma unroll
    for (int x = 0; x < 20; ++x) acc[x] = bz;
#pragma unroll
    for (int ky = 0; ky < 9; ++ky) {
      float rr[28];
#pragma unroll
      for (int q = 0; q < 7; ++q)
        *(float4*)&rr[q * 4] = *(const float4*)&simg[(yl + ky) * 36 + q * 4];
#pragma unroll
      for (int kx = 0; kx < 9; ++kx) {
        const float w = wr[ky * 9 + kx];
#pragma unroll
        for (int x = 0; x < 20; ++x) acc[x] = fmaf(w, rr[x + kx], acc[x]);
      }
    }
    const int chunk = ci >> 5, cil = ci & 31, kg = cil >> 3, il = cil & 7;
    short* base = c1g + ((size_t)(img * 8 + chunk) * 400) * 64;
    const int kapy = 6 * (y >> 1);
#pragma unroll
    for (int x = 0; x < 20; ++x) {
      const int row = y * 20 + x;
      const int kap = ((x >> 1) + kapy) & 7;
      const float v = fmaxf(acc[x], 0.f);
      const short hi = f2bf(v);
      const short lo = f2bf(v - bf2f(hi));
      base[row * 64 + (((kg + kap) & 7) << 3) + il] = hi;
      base[row * 64 + (((kg + 4 + kap) & 7) << 3) + il] = lo;
    }
  }
}

// ---------------- conv2 via MFMA, high-TLP ----------------
__global__ __launch_bounds__(256) void conv2_mfma(
    const short* __restrict__ c1g, const short* __restrict__ wstg,
    const float* __restrict__ b2, float* __restrict__ xcaps) {
  const int t = threadIdx.x;
  const int coh = blockIdx.x >> 8;   // co-major: XCD-mates share a slice
  const int img = blockIdx.x & 255;
  const int lane = t & 63;
  const int wv = t >> 6;             // 0..3
  const int r16 = lane & 15;
  const int kg = lane >> 4;

  __shared__ short c1[400 * 64];     // 51,200 B: [row][slot8][il8], swizzled

  // A-tile lane constants
  int arow[3], kap0[3];
#pragma unroll
  for (int m = 0; m < 3; ++m) {
    int pos = m * 16 + r16;
    if (pos > 35) pos = 35;          // clamped: same-addr broadcast, discarded
    const int oy = pos / 6, ox = pos % 6;
    arow[m] = oy * 40 + ox * 2;      // row at tap = arow + ky*20 + kx
    kap0[m] = ox + 6 * oy;           // kap = (kap0 + (kx>>1) + 6*(ky>>1)) & 7
  }
  const int co = coh * 64 + wv * 16 + r16;
  const int bOff = kg * 256 + co;    // wstg slot offset within tap
  const float bias = b2[co];

  const f32x4 vzero = {0.f, 0.f, 0.f, 0.f};
  f32x4 acc[3];
#pragma unroll
  for (int m = 0; m < 3; ++m) acc[m] = vzero;

  const s16x8* wsv = (const s16x8*)wstg;

  for (int chunk = 0; chunk < 8; ++chunk) {
    __syncthreads();  // previous chunk fully consumed
    {
      const short* src = c1g + ((size_t)(img * 8 + chunk) * 400) * 64;
      for (int c = wv; c < 50; c += 4)
        stage16(src + c * 512 + lane * 8, &c1[c * 512]);
    }
    __syncthreads();  // vmcnt drain: c1 chunk staged

    const size_t bb = (size_t)chunk * 81 * 2048 + bOff;
    s16x8 BHc = wsv[bb], BLc = wsv[bb + 1024];
    for (int ky = 0; ky < 9; ++ky) {
      const int rbase = ky * 20;
      const int kapky = 6 * (ky >> 1);
#pragma unroll
      for (int kx = 0; kx < 9; ++kx) {
        // depth-1 B prefetch (next tap, or none at chunk end)
        s16x8 BHn, BLn;
        const int tt = ky * 9 + kx;
        if (tt < 80) {
          const size_t nb = bb + (size_t)(tt + 1) * 2048;
          BHn = wsv[nb];
          BLn = wsv[nb + 1024];
        }
        // A fragments (swizzled, conflict-free)
        s16x8 AH[3], AL[3];
#pragma unroll
        for (int m = 0; m < 3; ++m) {
          const int row = arow[m] + rbase + kx;
          const int kap = kap0[m] + (kx >> 1) + kapky;
          const int ah = row * 64 + (((kg + kap) & 7) << 3);
          const int al = row * 64 + (((kg + 4 + kap) & 7) << 3);
          AH[m] = *(const s16x8*)&c1[ah];
          AL[m] = *(const s16x8*)&c1[al];
        }
#pragma unroll
        for (int m = 0; m < 3; ++m)
          acc[m] = __builtin_amdgcn_mfma_f32_16x16x32_bf16(AH[m], BHc, acc[m], 0, 0, 0);
#pragma unroll
        for (int m = 0; m < 3; ++m)
          acc[m] = __builtin_amdgcn_mfma_f32_16x16x32_bf16(AL[m], BHc, acc[m], 0, 0, 0);
#pragma unroll
        for (int m = 0; m < 3; ++m)
          acc[m] = __builtin_amdgcn_mfma_f32_16x16x32_bf16(AH[m], BLc, acc[m], 0, 0, 0);
        BHc = BHn;
        BLc = BLn;
      }
    }
  }

  // store: D col = r16 (co), row = kg*4 + reg (pos); xcaps[b][n][d]
#pragma unroll
  for (int m = 0; m < 3; ++m) {
#pragma unroll
    for (int jj = 0; jj < 4; ++jj) {
      const int pos = m * 16 + kg * 4 + jj;
      if (pos < 36) {
        const int n = (co & 31) * 36 + pos;
        xcaps[((size_t)img * 1152 + n) * 8 + (co >> 5)] = acc[m][jj] + bias;
      }
    }
  }
}

// ---------------- fused u_hat + routing: block per (o,b) ----------------
__global__ __launch_bounds__(256) void routing_fused(const float* __restrict__ xcaps,
                                                     const float* __restrict__ W,
                                                     float* __restrict__ out) {
  const int o = blockIdx.x >> 8;
  const int b = blockIdx.x & 255;
  const int t = threadIdx.x;
  const int k = t & 15, ng = t >> 4;
  __shared__ float xs[1152 * 9];
  __shared__ double redA[256];
  __shared__ double redB[256];
  __shared__ float s_s[16];
  __shared__ float s_sv;
  __shared__ double s_f;

  {
    const float4* src = (const float4*)(xcaps + (size_t)b * 9216);
    for (int idx = t; idx < 2304; idx += 256) {
      float4 v = src[idx];
      const int n = idx >> 1, h = idx & 1;
      float* dst = &xs[n * 9 + h * 4];
      dst[0] = v.x; dst[1] = v.y; dst[2] = v.z; dst[3] = v.w;
    }
  }
  __syncthreads();

  const int n0 = ng * 72;
  float u[72];
  const float* wp = W + ((size_t)(n0 * 10 + o) * 16 + k) * 8;
#pragma unroll
  for (int i = 0; i < 72; ++i) {
    const float* wq = wp + (size_t)i * 1280;
    const float4 wa = *(const float4*)wq;
    const float4 wb = *(const float4*)(wq + 4);
    const float* xp = &xs[(n0 + i) * 9];
    float s = fmaf(wa.x, xp[0], 0.f);
    s = fmaf(wa.y, xp[1], s);
    s = fmaf(wa.z, xp[2], s);
    s = fmaf(wa.w, xp[3], s);
    s = fmaf(wb.x, xp[4], s);
    s = fmaf(wb.y, xp[5], s);
    s = fmaf(wb.z, xp[6], s);
    s = fmaf(wb.w, xp[7], s);
    u[i] = s;
  }

  // pass 1: uniform c = 1/1152
  double S = 0.0;
#pragma unroll
  for (int i = 0; i < 72; ++i) S += (double)u[i];
  redA[t] = S;
  __syncthreads();
  if (t < 16) {
    double tt = 0.0;
#pragma unroll
    for (int g = 0; g < 16; ++g) tt += redA[g * 16 + t];
    s_s[t] = (float)(tt * (double)(1.0f / 1152.0f));
  }
  __syncthreads();
  if (t == 0) {
    double sn = 0.0;
#pragma unroll
    for (int kk = 0; kk < 16; ++kk) sn += (double)s_s[kk] * (double)s_s[kk];
    const double f = sn / ((1.0 + sn) * sqrt(sn));
    double sv = 0.0;
#pragma unroll
    for (int kk = 0; kk < 16; ++kk) sv += (double)s_s[kk] * f;
    s_sv = (float)sv;
  }
  __syncthreads();
  const float sv1 = s_sv;

  // pass 2
  double E = 0.0, EU = 0.0;
#pragma unroll
  for (int i = 0; i < 72; ++i) {
    const float e = expf(u[i] * sv1);
    E += (double)e;
    EU += (double)e * (double)u[i];
  }
  redA[t] = E; redB[t] = EU;
  __syncthreads();
  if (t < 16) {
    double te = 0.0, tu = 0.0;
#pragma unroll
    for (int g = 0; g < 16; ++g) { te += redA[g * 16 + t]; tu += redB[g * 16 + t]; }
    s_s[t] = (float)(tu / te);
  }
  __syncthreads();
  if (t == 0) {
    double sn = 0.0;
#pragma unroll
    for (int kk = 0; kk < 16; ++kk) sn += (double)s_s[kk] * (double)s_s[kk];
    const double f = sn / ((1.0 + sn) * sqrt(sn));
    double sv = 0.0;
#pragma unroll
    for (int kk = 0; kk < 16; ++kk) sv += (double)s_s[kk] * f;
    s_sv = sv1 + (float)sv;
  }
  __syncthreads();
  const float sv12 = s_sv;

  // pass 3 -> output
  E = 0.0; EU = 0.0;
#pragma unroll
  for (int i = 0; i < 72; ++i) {
    const float e = expf(u[i] * sv12);
    E += (double)e;
    EU += (double)e * (double)u[i];
  }
  redA[t] = E; redB[t] = EU;
  __syncthreads();
  if (t < 16) {
    double te = 0.0, tu = 0.0;
#pragma unroll
    for (int g = 0; g < 16; ++g) { te += redA[g * 16 + t]; tu += redB[g * 16 + t]; }
    s_s[t] = (float)(tu / te);
  }
  __syncthreads();
  if (t == 0) {
    double sn = 0.0;
#pragma unroll
    for (int kk = 0; kk < 16; ++kk) sn += (double)s_s[kk] * (double)s_s[kk];
    s_f = sn / ((1.0 + sn) * sqrt(sn));
  }
  __syncthreads();
  if (t < 16) out[b * 160 + o * 16 + t] = (float)((double)s_s[t] * s_f);
}

extern "C" void kernel_launch(void* const* d_in, const int* in_sizes, int n_in,
                              void* d_out, int out_size, void* d_ws, size_t ws_size,
                              hipStream_t stream) {
  const float* data = (const float*)d_in[0];
  const float* w1   = (const float*)d_in[1];
  const float* b1   = (const float*)d_in[2];
  const float* w2   = (const float*)d_in[3];
  const float* b2   = (const float*)d_in[4];
  const float* W    = (const float*)d_in[5];
  float* out = (float*)d_out;

  short* wstg  = (short*)d_ws;               // 10,616,832 shorts (21.2 MB)
  short* c1g   = wstg + 10616832;            // 52,428,800 shorts (104.9 MB)
  float* xcaps = (float*)(c1g + 52428800);   //  2,359,296 floats ( 9.4 MB)

  prep_w2<<<2592, 256, 0, stream>>>(w2, (s16x8*)wstg);
  conv1_c1g<<<512, 256, 0, stream>>>(data, w1, b1, c1g);
  conv2_mfma<<<1024, 256, 0, stream>>>(c1g, wstg, b2, xcaps);
  routing_fused<<<2560, 256, 0, stream>>>(xcaps, W, out);
}